// Round 8
// baseline (289.041 us; speedup 1.0000x reference)
//
#include <hip/hip_runtime.h>

// Depthwise 4x4 binomial blur, fp32, separable ([1,3,3,1]^T [1,3,3,1])/64.
// x: (8, 64, 512, 512), pad (1,1,1,1) -> out: (8, 64, 511, 511)
//
// One wave owns a full 512-wide x 128-row strip (8 cols/lane): 512 blocks
// (1 plane each), long sequential streams. Horizontal halo via intra-wave
// shuffles; vertical reuse in registers; 6-row register ring. No LDS/barriers.
// R8: all global accesses non-temporal (nt) via ext_vector_type pointers ->
// streaming replacement policy; input stream shouldn't evict in-flight output
// lines from L2.

constexpr int H  = 512;
constexpr int W  = 512;
constexpr int OH = 511;
constexpr int OW = 511;
constexpr int NPLANES = 8 * 64;

typedef float f4u __attribute__((ext_vector_type(4), aligned(4)));
typedef float f4a __attribute__((ext_vector_type(4), aligned(16)));

struct H8 { float v[8]; };
struct R2 { f4a b0, b1; };   // input cols 8l..8l+3, 8l+4..8l+7

__device__ __forceinline__ R2 ldrow(const float* __restrict__ ip, int gy, int cb)
{
    R2 r;
    r.b0 = (f4a){0.f, 0.f, 0.f, 0.f};
    r.b1 = r.b0;
    if ((unsigned)gy < (unsigned)H) {      // wave-uniform vertical pad
        const f4a* p = reinterpret_cast<const f4a*>(ip + (size_t)gy * W + cb);
        r.b0 = __builtin_nontemporal_load(p);
        r.b1 = __builtin_nontemporal_load(p + 1);
    }
    return r;
}

// horizontal [1,3,3,1] at cols cb-1..cb+9 -> h[0..7] for out cols cb..cb+7
__device__ __forceinline__ H8 hp8(const R2& r, bool l0, bool l63)
{
    float L  = __shfl_up(r.b1.w, 1);     // col cb-1 from lane-1
    float RX = __shfl_down(r.b0.x, 1);   // col cb+8 from lane+1
    float RY = __shfl_down(r.b0.y, 1);   // col cb+9 from lane+1
    L  = l0  ? 0.f : L;
    RX = l63 ? 0.f : RX;
    RY = l63 ? 0.f : RY;
    H8 h;
    h.v[0] = (L       + r.b0.z) + 3.f * (r.b0.x + r.b0.y);
    h.v[1] = (r.b0.x  + r.b0.w) + 3.f * (r.b0.y + r.b0.z);
    h.v[2] = (r.b0.y  + r.b1.x) + 3.f * (r.b0.z + r.b0.w);
    h.v[3] = (r.b0.z  + r.b1.y) + 3.f * (r.b0.w + r.b1.x);
    h.v[4] = (r.b0.w  + r.b1.z) + 3.f * (r.b1.x + r.b1.y);
    h.v[5] = (r.b1.x  + r.b1.w) + 3.f * (r.b1.y + r.b1.z);
    h.v[6] = (r.b1.y  + RX)     + 3.f * (r.b1.z + r.b1.w);
    h.v[7] = (r.b1.z  + RY)     + 3.f * (r.b1.w + RX);
    return h;
}

// vertical [1,3,3,1] combine + store 8 cols. OW=511: lane 63 stores an
// overlapping shifted dwordx4 (col 507 double-written, same value).
__device__ __forceinline__ void vst(float* __restrict__ op, int oy, int cb, bool l63,
                                    const H8& a, const H8& b, const H8& c, const H8& d)
{
    if (oy < OH) {                       // wave-uniform (only masks oy==511)
        float o[8];
        #pragma unroll
        for (int j = 0; j < 8; ++j)
            o[j] = ((a.v[j] + d.v[j]) + 3.f * (b.v[j] + c.v[j])) * 0.015625f;
        float* p = op + (size_t)oy * OW + cb;
        f4u s1 = { o[0], o[1], o[2], o[3] };
        f4u s2 = { l63 ? o[3] : o[4], l63 ? o[4] : o[5],
                   l63 ? o[5] : o[6], l63 ? o[6] : o[7] };
        __builtin_nontemporal_store(s1, reinterpret_cast<f4u*>(p));
        __builtin_nontemporal_store(s2, reinterpret_cast<f4u*>(p + (l63 ? 3 : 4)));
    }
}

__global__ __launch_bounds__(256)
void blur_kernel(const float* __restrict__ in, float* __restrict__ out)
{
    const int  tid  = threadIdx.x;
    const int  lane = tid & 63;
    const int  wv   = tid >> 6;
    const bool l0   = (lane == 0), l63 = (lane == 63);
    const int  cb   = lane * 8;

    const int plane = blockIdx.x;
    const int ys    = wv * 128;          // 128-row strip per wave

    const float* __restrict__ ip = in  + (size_t)plane * (H * W);
    float*       __restrict__ op = out + (size_t)plane * (OH * OW);

    // prologue: 9 rows of loads in flight before first use
    R2 r0 = ldrow(ip, ys - 1, cb);
    R2 r1 = ldrow(ip, ys,     cb);
    R2 r2 = ldrow(ip, ys + 1, cb);
    R2 P0 = ldrow(ip, ys + 2, cb);
    R2 P1 = ldrow(ip, ys + 3, cb);
    R2 P2 = ldrow(ip, ys + 4, cb);
    R2 P3 = ldrow(ip, ys + 5, cb);
    R2 P4 = ldrow(ip, ys + 6, cb);
    R2 P5 = ldrow(ip, ys + 7, cb);

    H8 hA = hp8(r0, l0, l63);
    H8 hB = hp8(r1, l0, l63);
    H8 hC = hp8(r2, l0, l63);

    // main: 20 trips x 6 rows (120 rows); refill row = consume row + 6
    int i = 0;
    #pragma unroll 1
    for (int t = 0; t < 20; ++t, i += 6) {
        H8 h3;
        h3 = hp8(P0, l0, l63); vst(op, ys + i + 0, cb, l63, hA, hB, hC, h3); P0 = ldrow(ip, ys + i + 8,  cb); hA = hB; hB = hC; hC = h3;
        h3 = hp8(P1, l0, l63); vst(op, ys + i + 1, cb, l63, hA, hB, hC, h3); P1 = ldrow(ip, ys + i + 9,  cb); hA = hB; hB = hC; hC = h3;
        h3 = hp8(P2, l0, l63); vst(op, ys + i + 2, cb, l63, hA, hB, hC, h3); P2 = ldrow(ip, ys + i + 10, cb); hA = hB; hB = hC; hC = h3;
        h3 = hp8(P3, l0, l63); vst(op, ys + i + 3, cb, l63, hA, hB, hC, h3); P3 = ldrow(ip, ys + i + 11, cb); hA = hB; hB = hC; hC = h3;
        h3 = hp8(P4, l0, l63); vst(op, ys + i + 4, cb, l63, hA, hB, hC, h3); P4 = ldrow(ip, ys + i + 12, cb); hA = hB; hB = hC; hC = h3;
        h3 = hp8(P5, l0, l63); vst(op, ys + i + 5, cb, l63, hA, hB, hC, h3); P5 = ldrow(ip, ys + i + 13, cb); hA = hB; hB = hC; hC = h3;
    }

    // tail: i == 120. Last two input rows issued first (6 rows of cover).
    R2 Q0 = ldrow(ip, ys + 128, cb);
    R2 Q1 = ldrow(ip, ys + 129, cb);
    {
        H8 h3;
        h3 = hp8(P0, l0, l63); vst(op, ys + 120, cb, l63, hA, hB, hC, h3); hA = hB; hB = hC; hC = h3;
        h3 = hp8(P1, l0, l63); vst(op, ys + 121, cb, l63, hA, hB, hC, h3); hA = hB; hB = hC; hC = h3;
        h3 = hp8(P2, l0, l63); vst(op, ys + 122, cb, l63, hA, hB, hC, h3); hA = hB; hB = hC; hC = h3;
        h3 = hp8(P3, l0, l63); vst(op, ys + 123, cb, l63, hA, hB, hC, h3); hA = hB; hB = hC; hC = h3;
        h3 = hp8(P4, l0, l63); vst(op, ys + 124, cb, l63, hA, hB, hC, h3); hA = hB; hB = hC; hC = h3;
        h3 = hp8(P5, l0, l63); vst(op, ys + 125, cb, l63, hA, hB, hC, h3); hA = hB; hB = hC; hC = h3;
        h3 = hp8(Q0, l0, l63); vst(op, ys + 126, cb, l63, hA, hB, hC, h3); hA = hB; hB = hC; hC = h3;
        h3 = hp8(Q1, l0, l63); vst(op, ys + 127, cb, l63, hA, hB, hC, h3);
    }
}

extern "C" void kernel_launch(void* const* d_in, const int* in_sizes, int n_in,
                              void* d_out, int out_size, void* d_ws, size_t ws_size,
                              hipStream_t stream)
{
    const float* x = (const float*)d_in[0];
    float* out = (float*)d_out;

    dim3 grid(NPLANES);   // 512 blocks: 1 plane each, 4 waves x 128-row strips
    dim3 block(256);
    blur_kernel<<<grid, block, 0, stream>>>(x, out);
}

// Round 9
// 245.049 us; speedup vs baseline: 1.1795x; 1.1795x over previous
//
#include <hip/hip_runtime.h>

// Depthwise 4x4 binomial blur, fp32, separable ([1,3,3,1]^T [1,3,3,1])/64.
// x: (8, 64, 512, 512), pad (1,1,1,1) -> out: (8, 64, 511, 511)
//
// R9: half-row waves. 512 blocks (1 plane each) x 512 threads (8 waves).
// Wave (s, side) owns rows [128s, 128s+128) x cols [256*side, 256*side+256):
// 4 cols/lane -> per-instruction-DENSE 1KB loads/stores. Wave pairs walk the
// same rows -> DRAM stream topology identical to R6 (4 regions/plane), but
// occupancy doubles to 16 waves/CU. Cross-half halo via one wave-uniform 8B
// load per row (L2-hot from sibling wave). Vertical reuse in registers,
// 6-row ring. No LDS, no barriers, no NT (R8 showed caches help).

constexpr int H  = 512;
constexpr int W  = 512;
constexpr int OH = 511;
constexpr int OW = 511;
constexpr int NPLANES = 8 * 64;

typedef float f4u __attribute__((ext_vector_type(4), aligned(4)));

struct R { float4 q; float2 hx; };   // q: cols c0..c0+3; hx: cross-half halo pair

__device__ __forceinline__ R ldrow(const float* __restrict__ ip, int gy, int side, int lane)
{
    R r;
    r.q  = make_float4(0.f, 0.f, 0.f, 0.f);
    r.hx = make_float2(0.f, 0.f);
    if ((unsigned)gy < (unsigned)H) {          // wave-uniform vertical pad
        const float* row = ip + (size_t)gy * W;
        r.q  = *reinterpret_cast<const float4*>(row + side * 256 + 4 * lane);
        // side 0 needs cols 256,257 (right halo); side 1 needs col 255 (left halo, .y)
        r.hx = *reinterpret_cast<const float2*>(row + (side ? 254 : 256));
    }
    return r;
}

// horizontal [1,3,3,1]: out cols c0..c0+3 need input cols c0-1 .. c0+5
__device__ __forceinline__ float4 hp4(const R& r, int side, bool l0, bool l63)
{
    float L  = __shfl_up(r.q.w, 1);      // col c0-1
    float RX = __shfl_down(r.q.x, 1);    // col c0+4
    float RY = __shfl_down(r.q.y, 1);    // col c0+5
    if (side == 0) {                     // wave-uniform branch
        if (l0)  L = 0.f;                // image left edge zero-pad
        if (l63) { RX = r.hx.x; RY = r.hx.y; }   // cols 256,257
    } else {
        if (l0)  L = r.hx.y;             // col 255
        if (l63) { RX = 0.f; RY = 0.f; } // image right edge zero-pad
    }
    float4 h;
    h.x = (L      + r.q.z) + 3.f * (r.q.x + r.q.y);
    h.y = (r.q.x  + r.q.w) + 3.f * (r.q.y + r.q.z);
    h.z = (r.q.y  + RX)    + 3.f * (r.q.z + r.q.w);
    h.w = (r.q.z  + RY)    + 3.f * (r.q.w + RX);
    return h;
}

// vertical [1,3,3,1] combine + store 4 cols. Side-1 lane 63 owns cols 508..511
// but col 511 doesn't exist: store a shifted dwordx4 at col 507 instead
// (col 507 re-written with lane 62's value, fetched via shuffle).
__device__ __forceinline__ void vst(float* __restrict__ op, int oy, int side, int lane,
                                    bool lastq,
                                    const float4& a, const float4& b,
                                    const float4& c, const float4& d)
{
    if (oy < OH) {                       // wave-uniform (only masks oy==511)
        float4 o;
        o.x = ((a.x + d.x) + 3.f * (b.x + c.x)) * 0.015625f;
        o.y = ((a.y + d.y) + 3.f * (b.y + c.y)) * 0.015625f;
        o.z = ((a.z + d.z) + 3.f * (b.z + c.z)) * 0.015625f;
        o.w = ((a.w + d.w) + 3.f * (b.w + c.w)) * 0.015625f;
        float ow = __shfl_up(o.w, 1);    // lane62's col-507 value for the shifted store
        float* p = op + (size_t)oy * OW + side * 256 + 4 * lane;
        if (lastq) {                     // side==1 && lane==63
            f4u s = { ow, o.x, o.y, o.z };
            *reinterpret_cast<f4u*>(p - 1) = s;      // cols 507..510
        } else {
            f4u s = { o.x, o.y, o.z, o.w };
            *reinterpret_cast<f4u*>(p) = s;
        }
    }
}

__global__ __launch_bounds__(512, 4)
void blur_kernel(const float* __restrict__ in, float* __restrict__ out)
{
    const int  tid  = threadIdx.x;
    const int  lane = tid & 63;
    const int  wv   = tid >> 6;          // 0..7
    const int  s    = wv >> 1;           // row strip 0..3
    const int  side = wv & 1;            // column half
    const bool l0   = (lane == 0), l63 = (lane == 63);
    const bool lastq = (side == 1) && l63;

    const int plane = blockIdx.x;
    const int ys    = s * 128;

    const float* __restrict__ ip = in  + (size_t)plane * (H * W);
    float*       __restrict__ op = out + (size_t)plane * (OH * OW);

    // prologue: 9 rows of loads in flight before first use
    R r0 = ldrow(ip, ys - 1, side, lane);
    R r1 = ldrow(ip, ys,     side, lane);
    R r2 = ldrow(ip, ys + 1, side, lane);
    R P0 = ldrow(ip, ys + 2, side, lane);
    R P1 = ldrow(ip, ys + 3, side, lane);
    R P2 = ldrow(ip, ys + 4, side, lane);
    R P3 = ldrow(ip, ys + 5, side, lane);
    R P4 = ldrow(ip, ys + 6, side, lane);
    R P5 = ldrow(ip, ys + 7, side, lane);

    float4 hA = hp4(r0, side, l0, l63);
    float4 hB = hp4(r1, side, l0, l63);
    float4 hC = hp4(r2, side, l0, l63);

    // main: 20 trips x 6 rows (120 rows); refill row = consume row + 6
    int i = 0;
    #pragma unroll 1
    for (int t = 0; t < 20; ++t, i += 6) {
        float4 h3;
        h3 = hp4(P0, side, l0, l63); vst(op, ys + i + 0, side, lane, lastq, hA, hB, hC, h3); P0 = ldrow(ip, ys + i + 8,  side, lane); hA = hB; hB = hC; hC = h3;
        h3 = hp4(P1, side, l0, l63); vst(op, ys + i + 1, side, lane, lastq, hA, hB, hC, h3); P1 = ldrow(ip, ys + i + 9,  side, lane); hA = hB; hB = hC; hC = h3;
        h3 = hp4(P2, side, l0, l63); vst(op, ys + i + 2, side, lane, lastq, hA, hB, hC, h3); P2 = ldrow(ip, ys + i + 10, side, lane); hA = hB; hB = hC; hC = h3;
        h3 = hp4(P3, side, l0, l63); vst(op, ys + i + 3, side, lane, lastq, hA, hB, hC, h3); P3 = ldrow(ip, ys + i + 11, side, lane); hA = hB; hB = hC; hC = h3;
        h3 = hp4(P4, side, l0, l63); vst(op, ys + i + 4, side, lane, lastq, hA, hB, hC, h3); P4 = ldrow(ip, ys + i + 12, side, lane); hA = hB; hB = hC; hC = h3;
        h3 = hp4(P5, side, l0, l63); vst(op, ys + i + 5, side, lane, lastq, hA, hB, hC, h3); P5 = ldrow(ip, ys + i + 13, side, lane); hA = hB; hB = hC; hC = h3;
    }

    // tail: i == 120. Last two input rows issued first (6 rows of cover).
    R Q0 = ldrow(ip, ys + 128, side, lane);
    R Q1 = ldrow(ip, ys + 129, side, lane);
    {
        float4 h3;
        h3 = hp4(P0, side, l0, l63); vst(op, ys + 120, side, lane, lastq, hA, hB, hC, h3); hA = hB; hB = hC; hC = h3;
        h3 = hp4(P1, side, l0, l63); vst(op, ys + 121, side, lane, lastq, hA, hB, hC, h3); hA = hB; hB = hC; hC = h3;
        h3 = hp4(P2, side, l0, l63); vst(op, ys + 122, side, lane, lastq, hA, hB, hC, h3); hA = hB; hB = hC; hC = h3;
        h3 = hp4(P3, side, l0, l63); vst(op, ys + 123, side, lane, lastq, hA, hB, hC, h3); hA = hB; hB = hC; hC = h3;
        h3 = hp4(P4, side, l0, l63); vst(op, ys + 124, side, lane, lastq, hA, hB, hC, h3); hA = hB; hB = hC; hC = h3;
        h3 = hp4(P5, side, l0, l63); vst(op, ys + 125, side, lane, lastq, hA, hB, hC, h3); hA = hB; hB = hC; hC = h3;
        h3 = hp4(Q0, side, l0, l63); vst(op, ys + 126, side, lane, lastq, hA, hB, hC, h3); hA = hB; hB = hC; hC = h3;
        h3 = hp4(Q1, side, l0, l63); vst(op, ys + 127, side, lane, lastq, hA, hB, hC, h3);
    }
}

extern "C" void kernel_launch(void* const* d_in, const int* in_sizes, int n_in,
                              void* d_out, int out_size, void* d_ws, size_t ws_size,
                              hipStream_t stream)
{
    const float* x = (const float*)d_in[0];
    float* out = (float*)d_out;

    dim3 grid(NPLANES);    // 512 blocks: 1 plane each
    dim3 block(512);       // 8 waves: 4 row-strips x 2 column halves
    blur_kernel<<<grid, block, 0, stream>>>(x, out);
}

// Round 10
// 237.710 us; speedup vs baseline: 1.2159x; 1.0309x over previous
//
#include <hip/hip_runtime.h>

// Depthwise 4x4 binomial blur, fp32, separable ([1,3,3,1]^T [1,3,3,1])/64.
// x: (8, 64, 512, 512), pad (1,1,1,1) -> out: (8, 64, 511, 511)
//
// R10: R6 base (512 blocks, 1 plane each; wave owns 512-wide x 128-row strip,
// 8 cols/lane; shuffle halo; h-carry in registers) + BURST-GROUPED phases:
// each half-trip issues 12 back-to-back row loads (6 rows) into one register
// bank (X/Y alternating, all-static indexing), then 6x compute + 12-store run.
// Longer same-direction VMEM runs per wave -> fewer DRAM R/W turnarounds.
// No LDS, no barriers, no NT.

constexpr int H  = 512;
constexpr int W  = 512;
constexpr int OH = 511;
constexpr int OW = 511;
constexpr int NPLANES = 8 * 64;

typedef float f4u __attribute__((ext_vector_type(4), aligned(4)));

struct H8 { float v[8]; };
struct R2 { float4 b0, b1; };   // input cols 8l..8l+3, 8l+4..8l+7

__device__ __forceinline__ R2 ldrow(const float* __restrict__ ip, int gy, int cb)
{
    R2 r;
    r.b0 = make_float4(0.f, 0.f, 0.f, 0.f);
    r.b1 = r.b0;
    if ((unsigned)gy < (unsigned)H) {      // wave-uniform vertical pad
        const float* p = ip + (size_t)gy * W + cb;
        r.b0 = *reinterpret_cast<const float4*>(p);
        r.b1 = *reinterpret_cast<const float4*>(p + 4);
    }
    return r;
}

// horizontal [1,3,3,1] at cols cb-1..cb+9 -> h[0..7] for out cols cb..cb+7
__device__ __forceinline__ H8 hp8(const R2& r, bool l0, bool l63)
{
    float L  = __shfl_up(r.b1.w, 1);     // col cb-1 from lane-1
    float RX = __shfl_down(r.b0.x, 1);   // col cb+8 from lane+1
    float RY = __shfl_down(r.b0.y, 1);   // col cb+9 from lane+1
    L  = l0  ? 0.f : L;
    RX = l63 ? 0.f : RX;
    RY = l63 ? 0.f : RY;
    H8 h;
    h.v[0] = (L       + r.b0.z) + 3.f * (r.b0.x + r.b0.y);
    h.v[1] = (r.b0.x  + r.b0.w) + 3.f * (r.b0.y + r.b0.z);
    h.v[2] = (r.b0.y  + r.b1.x) + 3.f * (r.b0.z + r.b0.w);
    h.v[3] = (r.b0.z  + r.b1.y) + 3.f * (r.b0.w + r.b1.x);
    h.v[4] = (r.b0.w  + r.b1.z) + 3.f * (r.b1.x + r.b1.y);
    h.v[5] = (r.b1.x  + r.b1.w) + 3.f * (r.b1.y + r.b1.z);
    h.v[6] = (r.b1.y  + RX)     + 3.f * (r.b1.z + r.b1.w);
    h.v[7] = (r.b1.z  + RY)     + 3.f * (r.b1.w + RX);
    return h;
}

// vertical [1,3,3,1] combine + store 8 cols. OW=511: lane 63 stores an
// overlapping shifted dwordx4 (col 507 double-written, same value).
__device__ __forceinline__ void vst(float* __restrict__ op, int oy, int cb, bool l63,
                                    const H8& a, const H8& b, const H8& c, const H8& d)
{
    if (oy < OH) {                       // wave-uniform (only masks oy==511)
        float o[8];
        #pragma unroll
        for (int j = 0; j < 8; ++j)
            o[j] = ((a.v[j] + d.v[j]) + 3.f * (b.v[j] + c.v[j])) * 0.015625f;
        float* p = op + (size_t)oy * OW + cb;
        *reinterpret_cast<f4u*>(p) = (f4u){o[0], o[1], o[2], o[3]};
        f4u s2 = { l63 ? o[3] : o[4], l63 ? o[4] : o[5],
                   l63 ? o[5] : o[6], l63 ? o[6] : o[7] };
        *reinterpret_cast<f4u*>(p + (l63 ? 3 : 4)) = s2;
    }
}

// consume one ring row: h3 = hp8(row); store output oy; rotate h-carry
#define CONSUME(ROW, OY)                                                      \
    { H8 h3 = hp8(ROW, l0, l63); vst(op, (OY), cb, l63, hA, hB, hC, h3);      \
      hA = hB; hB = hC; hC = h3; }

__global__ __launch_bounds__(256)
void blur_kernel(const float* __restrict__ in, float* __restrict__ out)
{
    const int  tid  = threadIdx.x;
    const int  lane = tid & 63;
    const int  wv   = tid >> 6;
    const bool l0   = (lane == 0), l63 = (lane == 63);
    const int  cb   = lane * 8;

    const int plane = blockIdx.x;
    const int ys    = wv * 128;          // 128-row strip per wave

    const float* __restrict__ ip = in  + (size_t)plane * (H * W);
    float*       __restrict__ op = out + (size_t)plane * (OH * OW);

    // prologue: carry rows + bank X (rows ys+2..ys+7)
    R2 r0 = ldrow(ip, ys - 1, cb);
    R2 r1 = ldrow(ip, ys,     cb);
    R2 r2 = ldrow(ip, ys + 1, cb);
    R2 X0 = ldrow(ip, ys + 2, cb);
    R2 X1 = ldrow(ip, ys + 3, cb);
    R2 X2 = ldrow(ip, ys + 4, cb);
    R2 X3 = ldrow(ip, ys + 5, cb);
    R2 X4 = ldrow(ip, ys + 6, cb);
    R2 X5 = ldrow(ip, ys + 7, cb);
    R2 Y0, Y1, Y2, Y3, Y4, Y5;

    H8 hA = hp8(r0, l0, l63);
    H8 hB = hp8(r1, l0, l63);
    H8 hC = hp8(r2, l0, l63);

    // main: 10 double-trips of 12 rows. Invariant at A-half start (output
    // base i): X holds input rows ys+i+2 .. ys+i+7, carry = h[ys+i-1..i+1].
    int i = 0;
    #pragma unroll 1
    for (int d = 0; d < 10; ++d) {
        // A-half: burst-issue Y = rows ys+i+8..13, then consume X -> outs i..i+5
        Y0 = ldrow(ip, ys + i + 8,  cb);
        Y1 = ldrow(ip, ys + i + 9,  cb);
        Y2 = ldrow(ip, ys + i + 10, cb);
        Y3 = ldrow(ip, ys + i + 11, cb);
        Y4 = ldrow(ip, ys + i + 12, cb);
        Y5 = ldrow(ip, ys + i + 13, cb);
        CONSUME(X0, ys + i + 0)
        CONSUME(X1, ys + i + 1)
        CONSUME(X2, ys + i + 2)
        CONSUME(X3, ys + i + 3)
        CONSUME(X4, ys + i + 4)
        CONSUME(X5, ys + i + 5)
        i += 6;
        // B-half: burst-issue X = rows ys+i+8..13, then consume Y -> outs i..i+5
        X0 = ldrow(ip, ys + i + 8,  cb);
        X1 = ldrow(ip, ys + i + 9,  cb);
        X2 = ldrow(ip, ys + i + 10, cb);
        X3 = ldrow(ip, ys + i + 11, cb);
        X4 = ldrow(ip, ys + i + 12, cb);
        X5 = ldrow(ip, ys + i + 13, cb);
        CONSUME(Y0, ys + i + 0)
        CONSUME(Y1, ys + i + 1)
        CONSUME(Y2, ys + i + 2)
        CONSUME(Y3, ys + i + 3)
        CONSUME(Y4, ys + i + 4)
        CONSUME(Y5, ys + i + 5)
        i += 6;
    }

    // tail: i == 120; X holds rows ys+122..127, carry = h[ys+119..121].
    // Rows ys+128, ys+129 guarded (zero for ys=384); oy==511 store masked.
    R2 Q0 = ldrow(ip, ys + 128, cb);
    R2 Q1 = ldrow(ip, ys + 129, cb);
    CONSUME(X0, ys + 120)
    CONSUME(X1, ys + 121)
    CONSUME(X2, ys + 122)
    CONSUME(X3, ys + 123)
    CONSUME(X4, ys + 124)
    CONSUME(X5, ys + 125)
    CONSUME(Q0, ys + 126)
    CONSUME(Q1, ys + 127)
}

extern "C" void kernel_launch(void* const* d_in, const int* in_sizes, int n_in,
                              void* d_out, int out_size, void* d_ws, size_t ws_size,
                              hipStream_t stream)
{
    const float* x = (const float*)d_in[0];
    float* out = (float*)d_out;

    dim3 grid(NPLANES);   // 512 blocks: 1 plane each, 4 waves x 128-row strips
    dim3 block(256);
    blur_kernel<<<grid, block, 0, stream>>>(x, out);
}

// Round 11
// 230.064 us; speedup vs baseline: 1.2563x; 1.0332x over previous
//
#include <hip/hip_runtime.h>

// Depthwise 4x4 binomial blur, fp32, separable ([1,3,3,1]^T [1,3,3,1])/64.
// x: (8, 64, 512, 512), pad (1,1,1,1) -> out: (8, 64, 511, 511)
//
// R11 = R6 + stream consolidation step 2: 256 blocks (1 per CU), each block
// processes 2 ADJACENT planes sequentially (plane 2b, then 2b+1). Concurrent
// DRAM streams: 1024 (vs R6's 2048), each 2x longer. Inner structure is R6
// verbatim: wave owns 512-wide x 128-row strip (8 cols/lane), shuffle halo,
// vertical reuse in registers, 6-row register ring. No LDS, no barriers.

constexpr int H  = 512;
constexpr int W  = 512;
constexpr int OH = 511;
constexpr int OW = 511;
constexpr int NPLANES = 8 * 64;

typedef float f4u __attribute__((ext_vector_type(4), aligned(4)));

struct H8 { float v[8]; };
struct R2 { float4 b0, b1; };   // input cols 8l..8l+3, 8l+4..8l+7

__device__ __forceinline__ R2 ldrow(const float* __restrict__ ip, int gy, int cb)
{
    R2 r;
    r.b0 = make_float4(0.f, 0.f, 0.f, 0.f);
    r.b1 = r.b0;
    if ((unsigned)gy < (unsigned)H) {      // wave-uniform vertical pad
        const float* p = ip + (size_t)gy * W + cb;
        r.b0 = *reinterpret_cast<const float4*>(p);
        r.b1 = *reinterpret_cast<const float4*>(p + 4);
    }
    return r;
}

// horizontal [1,3,3,1] at cols cb-1..cb+9 -> h[0..7] for out cols cb..cb+7
__device__ __forceinline__ H8 hp8(const R2& r, bool l0, bool l63)
{
    float L  = __shfl_up(r.b1.w, 1);     // col cb-1 from lane-1
    float RX = __shfl_down(r.b0.x, 1);   // col cb+8 from lane+1
    float RY = __shfl_down(r.b0.y, 1);   // col cb+9 from lane+1
    L  = l0  ? 0.f : L;
    RX = l63 ? 0.f : RX;
    RY = l63 ? 0.f : RY;
    H8 h;
    h.v[0] = (L       + r.b0.z) + 3.f * (r.b0.x + r.b0.y);
    h.v[1] = (r.b0.x  + r.b0.w) + 3.f * (r.b0.y + r.b0.z);
    h.v[2] = (r.b0.y  + r.b1.x) + 3.f * (r.b0.z + r.b0.w);
    h.v[3] = (r.b0.z  + r.b1.y) + 3.f * (r.b0.w + r.b1.x);
    h.v[4] = (r.b0.w  + r.b1.z) + 3.f * (r.b1.x + r.b1.y);
    h.v[5] = (r.b1.x  + r.b1.w) + 3.f * (r.b1.y + r.b1.z);
    h.v[6] = (r.b1.y  + RX)     + 3.f * (r.b1.z + r.b1.w);
    h.v[7] = (r.b1.z  + RY)     + 3.f * (r.b1.w + RX);
    return h;
}

// vertical [1,3,3,1] combine + store 8 cols. OW=511: lane 63 stores an
// overlapping shifted dwordx4 (col 507 double-written, same value).
__device__ __forceinline__ void vst(float* __restrict__ op, int oy, int cb, bool l63,
                                    const H8& a, const H8& b, const H8& c, const H8& d)
{
    if (oy < OH) {                       // wave-uniform (only masks oy==511)
        float o[8];
        #pragma unroll
        for (int j = 0; j < 8; ++j)
            o[j] = ((a.v[j] + d.v[j]) + 3.f * (b.v[j] + c.v[j])) * 0.015625f;
        float* p = op + (size_t)oy * OW + cb;
        *reinterpret_cast<f4u*>(p) = (f4u){o[0], o[1], o[2], o[3]};
        f4u s2 = { l63 ? o[3] : o[4], l63 ? o[4] : o[5],
                   l63 ? o[5] : o[6], l63 ? o[6] : o[7] };
        *reinterpret_cast<f4u*>(p + (l63 ? 3 : 4)) = s2;
    }
}

__global__ __launch_bounds__(256)
void blur_kernel(const float* __restrict__ in, float* __restrict__ out)
{
    const int  tid  = threadIdx.x;
    const int  lane = tid & 63;
    const int  wv   = tid >> 6;
    const bool l0   = (lane == 0), l63 = (lane == 63);
    const int  cb   = lane * 8;
    const int  ys   = wv * 128;          // 128-row strip per wave

    #pragma unroll 1
    for (int pp = 0; pp < 2; ++pp) {
        const int plane = blockIdx.x * 2 + pp;

        const float* __restrict__ ip = in  + (size_t)plane * (H * W);
        float*       __restrict__ op = out + (size_t)plane * (OH * OW);

        // prologue: 9 rows of loads in flight before first use
        R2 r0 = ldrow(ip, ys - 1, cb);
        R2 r1 = ldrow(ip, ys,     cb);
        R2 r2 = ldrow(ip, ys + 1, cb);
        R2 P0 = ldrow(ip, ys + 2, cb);
        R2 P1 = ldrow(ip, ys + 3, cb);
        R2 P2 = ldrow(ip, ys + 4, cb);
        R2 P3 = ldrow(ip, ys + 5, cb);
        R2 P4 = ldrow(ip, ys + 6, cb);
        R2 P5 = ldrow(ip, ys + 7, cb);

        H8 hA = hp8(r0, l0, l63);
        H8 hB = hp8(r1, l0, l63);
        H8 hC = hp8(r2, l0, l63);

        // main: 20 trips x 6 rows (120 rows); refill row = consume row + 6
        int i = 0;
        #pragma unroll 1
        for (int t = 0; t < 20; ++t, i += 6) {
            H8 h3;
            h3 = hp8(P0, l0, l63); vst(op, ys + i + 0, cb, l63, hA, hB, hC, h3); P0 = ldrow(ip, ys + i + 8,  cb); hA = hB; hB = hC; hC = h3;
            h3 = hp8(P1, l0, l63); vst(op, ys + i + 1, cb, l63, hA, hB, hC, h3); P1 = ldrow(ip, ys + i + 9,  cb); hA = hB; hB = hC; hC = h3;
            h3 = hp8(P2, l0, l63); vst(op, ys + i + 2, cb, l63, hA, hB, hC, h3); P2 = ldrow(ip, ys + i + 10, cb); hA = hB; hB = hC; hC = h3;
            h3 = hp8(P3, l0, l63); vst(op, ys + i + 3, cb, l63, hA, hB, hC, h3); P3 = ldrow(ip, ys + i + 11, cb); hA = hB; hB = hC; hC = h3;
            h3 = hp8(P4, l0, l63); vst(op, ys + i + 4, cb, l63, hA, hB, hC, h3); P4 = ldrow(ip, ys + i + 12, cb); hA = hB; hB = hC; hC = h3;
            h3 = hp8(P5, l0, l63); vst(op, ys + i + 5, cb, l63, hA, hB, hC, h3); P5 = ldrow(ip, ys + i + 13, cb); hA = hB; hB = hC; hC = h3;
        }

        // tail: i == 120. Last two input rows issued first (6 rows of cover).
        R2 Q0 = ldrow(ip, ys + 128, cb);
        R2 Q1 = ldrow(ip, ys + 129, cb);
        {
            H8 h3;
            h3 = hp8(P0, l0, l63); vst(op, ys + 120, cb, l63, hA, hB, hC, h3); hA = hB; hB = hC; hC = h3;
            h3 = hp8(P1, l0, l63); vst(op, ys + 121, cb, l63, hA, hB, hC, h3); hA = hB; hB = hC; hC = h3;
            h3 = hp8(P2, l0, l63); vst(op, ys + 122, cb, l63, hA, hB, hC, h3); hA = hB; hB = hC; hC = h3;
            h3 = hp8(P3, l0, l63); vst(op, ys + 123, cb, l63, hA, hB, hC, h3); hA = hB; hB = hC; hC = h3;
            h3 = hp8(P4, l0, l63); vst(op, ys + 124, cb, l63, hA, hB, hC, h3); hA = hB; hB = hC; hC = h3;
            h3 = hp8(P5, l0, l63); vst(op, ys + 125, cb, l63, hA, hB, hC, h3); hA = hB; hB = hC; hC = h3;
            h3 = hp8(Q0, l0, l63); vst(op, ys + 126, cb, l63, hA, hB, hC, h3); hA = hB; hB = hC; hC = h3;
            h3 = hp8(Q1, l0, l63); vst(op, ys + 127, cb, l63, hA, hB, hC, h3);
        }
    }
}

extern "C" void kernel_launch(void* const* d_in, const int* in_sizes, int n_in,
                              void* d_out, int out_size, void* d_ws, size_t ws_size,
                              hipStream_t stream)
{
    const float* x = (const float*)d_in[0];
    float* out = (float*)d_out;

    dim3 grid(NPLANES / 2);   // 256 blocks (1/CU): 2 adjacent planes each
    dim3 block(256);
    blur_kernel<<<grid, block, 0, stream>>>(x, out);
}